// Round 4
// baseline (579.138 us; speedup 1.0000x reference)
//
#include <hip/hip_runtime.h>
#include <hip/hip_bf16.h>
#include <math.h>

#define NH 8
#define L 512
#define DP 128
#define DS 16
#define DCAT 1280
#define TJ 32            // j-rows of e per tile
#define NCHUNK 4         // blocks per (b,i) row
#define CJ 128           // j-rows per chunk
#define PSTRIDE 1280     // floats per partial row

#define SCALE_SCALAR 0.25f
#define SCALE_POINT  0.23570226039551584f   // (4.5*4)^-0.5
#define SCALE_TOTAL  0.5773502691896258f    // 3^-0.5

typedef __bf16 bf16_t;
typedef bf16_t bf16x8 __attribute__((ext_vector_type(8)));
typedef bf16_t bf16x4 __attribute__((ext_vector_type(4)));
typedef float  f32x4v __attribute__((ext_vector_type(4)));

// ---------------------------------------------------------------------------
// k_pack: x -> bf16 (row-major 1024x384), all six W -> WallT (672x384 bf16)
// ---------------------------------------------------------------------------
__global__ __launch_bounds__(256) void k_pack(
    const float* __restrict__ x,
    const float* __restrict__ Wq_s, const float* __restrict__ Wk_s, const float* __restrict__ Wv_s,
    const float* __restrict__ Wq_p, const float* __restrict__ Wk_p, const float* __restrict__ Wv_p,
    __hip_bfloat16* __restrict__ xb, __hip_bfloat16* __restrict__ WallT) {
    int idx = blockIdx.x * 256 + threadIdx.x;          // 651264 total
    const int T1 = 1024 * 384;
    if (idx < T1) {
        xb[idx] = __float2bfloat16(x[idx]);
    } else {
        int j = idx - T1;                              // 0 .. 258047
        int n = j / 384, k = j % 384;
        float v;
        if      (n < 128) v = Wq_s[k * 128 + n];
        else if (n < 256) v = Wk_s[k * 128 + (n - 128)];
        else if (n < 384) v = Wv_s[k * 128 + (n - 256)];
        else if (n < 480) v = Wq_p[k * 96  + (n - 384)];
        else if (n < 576) v = Wk_p[k * 96  + (n - 480)];
        else              v = Wv_p[k * 96  + (n - 576)];
        WallT[(size_t)n * 384 + k] = __float2bfloat16(v);
    }
}

// ---------------------------------------------------------------------------
// k_prep: Wout (1280,384) fp32 -> WoutT (384,1280) bf16, tiled LDS transpose
// ---------------------------------------------------------------------------
__global__ __launch_bounds__(256) void k_prep(const float* __restrict__ Wout,
                                              __hip_bfloat16* __restrict__ WoutT) {
    __shared__ float tile[64][65];
    const int tid = threadIdx.x;
    const int k0 = blockIdx.x * 64;
    const int n0 = blockIdx.y * 64;
#pragma unroll
    for (int s = 0; s < 16; ++s) {
        int idx = s * 256 + tid, kk = idx >> 6, nn = idx & 63;
        tile[kk][nn] = Wout[(size_t)(k0 + kk) * 384 + n0 + nn];
    }
    __syncthreads();
#pragma unroll
    for (int s = 0; s < 16; ++s) {
        int idx = s * 256 + tid, nn = idx >> 6, kk = idx & 63;
        WoutT[(size_t)(n0 + nn) * 1280 + k0 + kk] = __float2bfloat16(tile[kk][nn]);
    }
}

// ---------------------------------------------------------------------------
// k_projm: [1024,672] = xb[1024,384] @ Wall[384,672]  (bf16 MFMA, fp32 out)
// also writes v_sT (bf16, [b,n][d][j]) for the MFMA-friendly sv pass
// ---------------------------------------------------------------------------
__global__ __launch_bounds__(256) void k_projm(
    const __hip_bfloat16* __restrict__ xb, const __hip_bfloat16* __restrict__ WallT,
    float* __restrict__ q_s, float* __restrict__ k_s, float* __restrict__ v_s,
    float* __restrict__ praw, __hip_bfloat16* __restrict__ v_sT) {
    __shared__ __align__(16) bf16_t As[64 * 40];
    __shared__ __align__(16) bf16_t Bs[48 * 40];
    const int tid = threadIdx.x;
    const int row0 = blockIdx.x * 64, col0 = blockIdx.y * 48;
    const int w = tid >> 6, lane = tid & 63;
    f32x4v acc[3] = {};

    for (int k0 = 0; k0 < 384; k0 += 32) {
        __syncthreads();
        {
            int rr = tid >> 2, q = tid & 3;
            *reinterpret_cast<int4*>(&As[rr * 40 + q * 8]) =
                *reinterpret_cast<const int4*>(&xb[(size_t)(row0 + rr) * 384 + k0 + q * 8]);
            if (tid < 192)
                *reinterpret_cast<int4*>(&Bs[rr * 40 + q * 8]) =
                    *reinterpret_cast<const int4*>(&WallT[(size_t)(col0 + rr) * 384 + k0 + q * 8]);
        }
        __syncthreads();
        const int m = lane & 15, kq = lane >> 4;
        bf16x8 af = *reinterpret_cast<const bf16x8*>(&As[(w * 16 + m) * 40 + kq * 8]);
#pragma unroll
        for (int c = 0; c < 3; ++c) {
            bf16x8 bfr = *reinterpret_cast<const bf16x8*>(&Bs[(c * 16 + m) * 40 + kq * 8]);
            acc[c] = __builtin_amdgcn_mfma_f32_16x16x32_bf16(af, bfr, acc[c], 0, 0, 0);
        }
    }
    const int colL = lane & 15, rbase = (lane >> 4) * 4;
#pragma unroll
    for (int c = 0; c < 3; ++c) {
        int col = col0 + c * 16 + colL;
#pragma unroll
        for (int rg = 0; rg < 4; ++rg) {
            int row = row0 + w * 16 + rbase + rg;
            float v = acc[c][rg];
            int bb = row >> 9, ll = row & 511;
            if (col < 384) {
                int kind = col >> 7, n = (col >> 4) & 7, d = col & 15;
                float* dst = (kind == 0) ? q_s : (kind == 1) ? k_s : v_s;
                dst[((size_t)(bb * NH + n) * L + ll) * DS + d] = v;
                if (kind == 2)
                    v_sT[((size_t)((bb * NH + n) * DS + d)) * L + ll] = __float2bfloat16(v);
            } else {
                praw[(size_t)row * 288 + (col - 384)] = v;
            }
        }
    }
}

// ---------------------------------------------------------------------------
// k_euclid: praw -> q_p/k_p/v_p (forward euclid), plus v_pT bf16 transposed
// ---------------------------------------------------------------------------
__global__ __launch_bounds__(256) void k_euclid(
    const float* __restrict__ praw, const float* __restrict__ r, const float* __restrict__ t,
    float* __restrict__ q_p, float* __restrict__ k_p, float* __restrict__ v_p,
    __hip_bfloat16* __restrict__ v_pT) {
    int idx = blockIdx.x * 256 + threadIdx.x;          // 294912 total
    int row = idx / 288, o = idx % 288;
    int arr = o / 96, oo = o % 96;
    int n = oo / 12, pc = oo % 12, p = pc / 3, c = pc % 3;
    const float* base = praw + (size_t)row * 288 + arr * 96 + n * 12 + p * 3;
    float acc = t[row * 3 + c];
#pragma unroll
    for (int k = 0; k < 3; ++k) acc += base[k] * r[row * 9 + k * 3 + c];
    float* dst = (arr == 0) ? q_p : (arr == 1) ? k_p : v_p;
    int bb = row >> 9, ll = row & 511;
    dst[((size_t)(bb * NH + n) * L + ll) * 12 + pc] = acc;
    if (arr == 2)
        v_pT[((size_t)((bb * NH + n) * 12 + pc)) * L + ll] = __float2bfloat16(acc);
}

// ---------------------------------------------------------------------------
// k_attn: per (b,i,chunk). MFMA for bias (e@Wpb) and pair (P@e); scalar fp32
// for qk/point logits; sv from pre-transposed bf16 v. e staged bf16 in two
// layouts, register-prefetched one tile ahead.
// LDS strides (shorts): etA row 136 (128d+pad), etB row 40 (32j+pad), pT row 40.
// ---------------------------------------------------------------------------
__global__ __launch_bounds__(256, 4) void k_attn(
    const float* __restrict__ e, const float* __restrict__ Wpb, const float* __restrict__ gamma,
    const float* __restrict__ q_s, const float* __restrict__ k_s,
    const float* __restrict__ q_p, const float* __restrict__ k_p,
    const __hip_bfloat16* __restrict__ v_sT, const __hip_bfloat16* __restrict__ v_pT,
    float* __restrict__ part) {
    __shared__ __align__(16) bf16_t etA[TJ * 136];     // [j][d] bf16
    __shared__ __align__(16) bf16_t etB[DP * 40];      // [d][j] bf16
    __shared__ __align__(16) bf16_t pT[16 * 40];       // [head][j] bf16 (rows 8..15 zero)
    __shared__ __align__(16) float pt32[NH * 36];      // [head][j] fp32 for sv
    __shared__ __align__(16) float qsl[NH * 16];
    __shared__ __align__(16) float qpl[NH * 12];
    __shared__ float csh[NH];                           // ST*0.5*SP*gamma[n]
    __shared__ float lsumw[16];

    const int tid = threadIdx.x;
    const int blk = blockIdx.x;
    const int bi = blk >> 2, chunk = blk & 3;
    const int b = bi >> 9, i = bi & 511, b8 = b * NH;
    const int w = tid >> 6, lane = tid & 63;
    const int c15 = lane & 15, quad = lane >> 4;

    // ---- init ----
    if (tid < 128) {
        int n = tid >> 4, d = tid & 15;
        qsl[n * 16 + d] = q_s[((size_t)(b8 + n) * L + i) * DS + d];
    } else if (tid < 224) {
        int o = tid - 128, n = o / 12, pc = o % 12;
        qpl[n * 12 + pc] = q_p[((size_t)(b8 + n) * L + i) * 12 + pc];
    } else if (tid < 232) {
        int n = tid - 224;
        csh[n] = SCALE_TOTAL * 0.5f * SCALE_POINT * gamma[n];
    }
    // Wpb B-fragments (K=128 over 4 k-steps), scaled by SCALE_TOTAL, regs
    bf16x8 wpbF[4];
#pragma unroll
    for (int ks = 0; ks < 4; ++ks)
#pragma unroll
        for (int ii = 0; ii < 8; ++ii) {
            int d = ks * 32 + quad * 8 + ii;
            float wv = (c15 < 8) ? Wpb[d * NH + c15] : 0.f;
            wpbF[ks][ii] = (bf16_t)(SCALE_TOTAL * wv);
        }

    const float4* esrc4 = reinterpret_cast<const float4*>(
        e + ((size_t)(b * L + i) * L + chunk * CJ) * DP);

    // prologue: prefetch tile 0 into registers
    float4 pre[4];
#pragma unroll
    for (int s = 0; s < 4; ++s) {
        int idx = tid + s * 256, j = idx >> 5, g = idx & 31;
        pre[s] = esrc4[(size_t)j * 32 + g];
    }

    f32x4v accP[2] = {};
    float accS = 0.f, accP3 = 0.f, lsum = 0.f;
    const int tid2 = tid - 128;                       // sv index for waves 2,3
    const int nS = (tid2 >= 0) ? (tid2 >> 4) : 0, dS = (tid2 >= 0) ? (tid2 & 15) : 0;
    const int nP = (tid2 >= 0 && tid2 < 96) ? tid2 / 12 : 0;
    const int pcP = (tid2 >= 0 && tid2 < 96) ? tid2 % 12 : 0;
    const __hip_bfloat16* vsp = v_sT + ((size_t)((b8 + nS) * DS + dS)) * L + chunk * CJ;
    const __hip_bfloat16* vpp = v_pT + ((size_t)((b8 + nP) * 12 + pcP)) * L + chunk * CJ;

    for (int tt = 0; tt < CJ / TJ; ++tt) {
        __syncthreads();                               // (1) et free, pt32 consumed
        // ---- stage pre -> etA (row-major) + etB (transposed) ----
#pragma unroll
        for (int s = 0; s < 4; ++s) {
            int idx = tid + s * 256, j = idx >> 5, g = idx & 31;
            float4 v = pre[s];
            bf16x4 a;
            a[0] = (bf16_t)v.x; a[1] = (bf16_t)v.y; a[2] = (bf16_t)v.z; a[3] = (bf16_t)v.w;
            *reinterpret_cast<bf16x4*>(&etA[j * 136 + 4 * g]) = a;
            etB[(4 * g + 0) * 40 + j] = a[0];
            etB[(4 * g + 1) * 40 + j] = a[1];
            etB[(4 * g + 2) * 40 + j] = a[2];
            etB[(4 * g + 3) * 40 + j] = a[3];
        }
        // prefetch next tile
        if (tt < CJ / TJ - 1) {
#pragma unroll
            for (int s = 0; s < 4; ++s) {
                int idx = tid + s * 256, j = idx >> 5, g = idx & 31;
                pre[s] = esrc4[(size_t)(tt + 1) * TJ * 32 + (size_t)j * 32 + g];
            }
        }
        __syncthreads();                               // (2) et ready
        // ---- waves 0,1: logits (bias MFMA + fp32 scalar/point) ----
        if (w < 2) {
            f32x4v bc = {};
#pragma unroll
            for (int ks = 0; ks < 4; ++ks) {
                bf16x8 af = *reinterpret_cast<const bf16x8*>(
                    &etA[(w * 16 + c15) * 136 + ks * 32 + quad * 8]);
                bc = __builtin_amdgcn_mfma_f32_16x16x32_bf16(af, wpbF[ks], bc, 0, 0, 0);
            }
            // lane holds bias*ST for (head=c15, j = w*16 + quad*4 + r)
            const int n = c15;
#pragma unroll
            for (int r = 0; r < 4; ++r) {
                int jl = w * 16 + quad * 4 + r;
                float pv = 0.f;
                if (n < 8) {
                    int jg = chunk * CJ + tt * TJ + jl;
                    const float4* ksr = reinterpret_cast<const float4*>(
                        k_s + (((size_t)(b8 + n) * L + jg) << 4));
                    const float4* q4 = reinterpret_cast<const float4*>(&qsl[n * 16]);
                    float ss = 0.f;
#pragma unroll
                    for (int g = 0; g < 4; ++g) {
                        float4 kv = ksr[g], qv = q4[g];
                        ss += kv.x * qv.x + kv.y * qv.y + kv.z * qv.z + kv.w * qv.w;
                    }
                    const float4* kpr = reinterpret_cast<const float4*>(
                        k_p + ((size_t)(b8 + n) * L + jg) * 12);
                    const float4* qp4 = reinterpret_cast<const float4*>(&qpl[n * 12]);
                    float sq = 0.f;
#pragma unroll
                    for (int g = 0; g < 3; ++g) {
                        float4 kv = kpr[g], qv = qp4[g];
                        float d0;
                        d0 = qv.x - kv.x; sq += d0 * d0;  d0 = qv.y - kv.y; sq += d0 * d0;
                        d0 = qv.z - kv.z; sq += d0 * d0;  d0 = qv.w - kv.w; sq += d0 * d0;
                    }
                    float lg = bc[r] + (SCALE_TOTAL * SCALE_SCALAR) * ss - csh[n] * sq;
                    pv = __expf(lg);
                    pt32[n * 36 + jl] = pv;
                }
                lsum += pv;
                pT[n * 40 + jl] = (bf16_t)pv;
            }
        }
        __syncthreads();                               // (3) pT/pt32 ready
        // ---- all waves: pair MFMA (accumulate over tiles) ----
        {
            bf16x8 ap = *reinterpret_cast<const bf16x8*>(&pT[c15 * 40 + quad * 8]);
#pragma unroll
            for (int tb = 0; tb < 2; ++tb) {
                int d = (w * 2 + tb) * 16 + c15;
                bf16x8 bfr = *reinterpret_cast<const bf16x8*>(&etB[d * 40 + quad * 8]);
                accP[tb] = __builtin_amdgcn_mfma_f32_16x16x32_bf16(ap, bfr, accP[tb], 0, 0, 0);
            }
        }
        // ---- waves 2,3: sv for this tile ----
        if (w >= 2) {
            {
                const __hip_bfloat16* vp = vsp + tt * TJ;
#pragma unroll
                for (int q = 0; q < 4; ++q) {
                    bf16x8 vv = *reinterpret_cast<const bf16x8*>(vp + q * 8);
                    float4 pA = *reinterpret_cast<const float4*>(&pt32[nS * 36 + q * 8]);
                    float4 pB = *reinterpret_cast<const float4*>(&pt32[nS * 36 + q * 8 + 4]);
                    accS += pA.x * (float)vv[0] + pA.y * (float)vv[1]
                          + pA.z * (float)vv[2] + pA.w * (float)vv[3]
                          + pB.x * (float)vv[4] + pB.y * (float)vv[5]
                          + pB.z * (float)vv[6] + pB.w * (float)vv[7];
                }
            }
            if (tid2 < 96) {
                const __hip_bfloat16* vp = vpp + tt * TJ;
#pragma unroll
                for (int q = 0; q < 4; ++q) {
                    bf16x8 vv = *reinterpret_cast<const bf16x8*>(vp + q * 8);
                    float4 pA = *reinterpret_cast<const float4*>(&pt32[nP * 36 + q * 8]);
                    float4 pB = *reinterpret_cast<const float4*>(&pt32[nP * 36 + q * 8 + 4]);
                    accP3 += pA.x * (float)vv[0] + pA.y * (float)vv[1]
                           + pA.z * (float)vv[2] + pA.w * (float)vv[3]
                           + pB.x * (float)vv[4] + pB.y * (float)vv[5]
                           + pB.z * (float)vv[6] + pB.w * (float)vv[7];
                }
            }
        }
    }

    // ---- epilogue: reductions + partial writes ----
    lsum += __shfl_xor(lsum, 16);
    lsum += __shfl_xor(lsum, 32);
    if (w < 2 && lane < 8) lsumw[w * 8 + lane] = lsum;
    __syncthreads();

    float* prow = part + (size_t)blk * PSTRIDE;
    if (w >= 2) {
        prow[1024 + tid2] = accS;
        if (tid2 < 96) prow[1152 + tid2] = accP3;
    }
    if (quad < 2) {
#pragma unroll
        for (int tb = 0; tb < 2; ++tb)
#pragma unroll
            for (int r = 0; r < 4; ++r) {
                int h = quad * 4 + r;                  // head 0..7
                prow[h * 128 + (w * 2 + tb) * 16 + c15] = accP[tb][r];
            }
    }
    if (tid < 8) prow[1248 + tid] = lsumw[tid] + lsumw[8 + tid];
}

// ---------------------------------------------------------------------------
// k_comb: combine 4 chunk-partials per (b,i); normalize; epilogue; write concat
// ---------------------------------------------------------------------------
__global__ __launch_bounds__(256) void k_comb(
    const float* __restrict__ part, const float* __restrict__ r, const float* __restrict__ t,
    __hip_bfloat16* __restrict__ concat) {
    __shared__ float comb[1256];
    __shared__ float rtsh[12], osh[96], o2sh[96];
    const int tid = threadIdx.x;
    const int bi = blockIdx.x;
    const float* base = part + (size_t)bi * NCHUNK * PSTRIDE;
#pragma unroll
    for (int s = 0; s < 5; ++s) {
        int idx = tid + s * 256;
        if (idx < 1256)
            comb[idx] = base[idx] + base[PSTRIDE + idx] + base[2 * PSTRIDE + idx] + base[3 * PSTRIDE + idx];
    }
    if (tid >= 244 && tid < 256) {
        int c = tid - 244;
        rtsh[c] = (c < 9) ? r[bi * 9 + c] : t[bi * 3 + (c - 9)];
    }
    __syncthreads();
    __hip_bfloat16* crow = concat + (size_t)bi * DCAT;
    if (tid < 128) crow[tid] = __float2bfloat16(comb[1024 + tid] / comb[1248 + (tid >> 4)]);
    for (int idx = tid; idx < 1024; idx += 256)
        crow[128 + idx] = __float2bfloat16(comb[idx] / comb[1248 + (idx >> 7)]);
    if (tid >= 128 && tid < 224) {
        int o = tid - 128;
        osh[o] = comb[1152 + o] / comb[1248 + o / 12];
    }
    __syncthreads();
    if (tid < 96) {   // inverse euclid: o_c = sum_k (op_k - t_k) * r[c][k]
        int n = tid / 12, pc = tid % 12, p = pc / 3, c = pc % 3;
        float oc = 0.f;
#pragma unroll
        for (int k = 0; k < 3; ++k)
            oc += (osh[n * 12 + p * 3 + k] - rtsh[9 + k]) * rtsh[c * 3 + k];
        crow[1152 + tid] = __float2bfloat16(oc);
        o2sh[tid] = oc;
    }
    __syncthreads();
    if (tid < 32) {
        int n = tid >> 2, p = tid & 3;
        float vx = o2sh[n * 12 + p * 3], vy = o2sh[n * 12 + p * 3 + 1], vz = o2sh[n * 12 + p * 3 + 2];
        crow[1248 + tid] = __float2bfloat16(sqrtf(vx * vx + vy * vy + vz * vz));
    }
}

// ---------------------------------------------------------------------------
// k_out: bf16 MFMA GEMM: out[1024,384] = concat[1024,1280] @ Wout + bout
// ---------------------------------------------------------------------------
__global__ __launch_bounds__(256) void k_out(const __hip_bfloat16* __restrict__ A,
                                             const __hip_bfloat16* __restrict__ Bt,
                                             const float* __restrict__ bout,
                                             float* __restrict__ out) {
    __shared__ __align__(16) bf16_t At[64 * 40];
    __shared__ __align__(16) bf16_t Bs[64 * 40];
    const int tid = threadIdx.x;
    const int row0 = blockIdx.x * 64, col0 = blockIdx.y * 64;
    const int wv = tid >> 6, lane = tid & 63;
    f32x4v acc[4] = {};

    for (int k0 = 0; k0 < 1280; k0 += 32) {
        __syncthreads();
        {
            int rr = tid >> 2, q = tid & 3;
            *reinterpret_cast<int4*>(&At[rr * 40 + q * 8]) =
                *reinterpret_cast<const int4*>(&A[(size_t)(row0 + rr) * 1280 + k0 + q * 8]);
            *reinterpret_cast<int4*>(&Bs[rr * 40 + q * 8]) =
                *reinterpret_cast<const int4*>(&Bt[(size_t)(col0 + rr) * 1280 + k0 + q * 8]);
        }
        __syncthreads();
        const int m = lane & 15, kq = lane >> 4;
        bf16x8 af = *reinterpret_cast<const bf16x8*>(&At[(wv * 16 + m) * 40 + kq * 8]);
#pragma unroll
        for (int nt = 0; nt < 4; ++nt) {
            bf16x8 bfr = *reinterpret_cast<const bf16x8*>(&Bs[(nt * 16 + m) * 40 + kq * 8]);
            acc[nt] = __builtin_amdgcn_mfma_f32_16x16x32_bf16(af, bfr, acc[nt], 0, 0, 0);
        }
    }
    const int col_l = lane & 15, rbase = (lane >> 4) * 4;
#pragma unroll
    for (int nt = 0; nt < 4; ++nt) {
        int col = col0 + nt * 16 + col_l;
        float bo = bout[col];
#pragma unroll
        for (int rg = 0; rg < 4; ++rg) {
            int rowg = row0 + wv * 16 + rbase + rg;
            out[(size_t)rowg * 384 + col] = acc[nt][rg] + bo;
        }
    }
}

// ---------------------------------------------------------------------------
extern "C" void kernel_launch(void* const* d_in, const int* in_sizes, int n_in,
                              void* d_out, int out_size, void* d_ws, size_t ws_size,
                              hipStream_t stream) {
    const float* x     = (const float*)d_in[0];
    const float* e     = (const float*)d_in[1];
    const float* r     = (const float*)d_in[2];
    const float* t     = (const float*)d_in[3];
    const float* Wq_s  = (const float*)d_in[4];
    const float* Wk_s  = (const float*)d_in[5];
    const float* Wv_s  = (const float*)d_in[6];
    const float* Wpb   = (const float*)d_in[7];
    const float* Wq_p  = (const float*)d_in[8];
    const float* Wk_p  = (const float*)d_in[9];
    const float* Wv_p  = (const float*)d_in[10];
    const float* gamma = (const float*)d_in[11];
    const float* Wout  = (const float*)d_in[12];
    const float* bout  = (const float*)d_in[13];

    float* ws   = (float*)d_ws;
    float* q_s  = ws + 0;          // 131072
    float* k_s  = ws + 131072;     // 131072
    float* v_s  = ws + 262144;     // 131072
    float* q_p  = ws + 393216;     // 98304
    float* k_p  = ws + 491520;     // 98304
    float* v_p  = ws + 589824;     // 98304
    float* praw = ws + 688128;     // 294912
    __hip_bfloat16* xb     = (__hip_bfloat16*)((char*)d_ws + 3932160);  // 393216 bf16
    __hip_bfloat16* WallT  = (__hip_bfloat16*)((char*)d_ws + 4718592);  // 258048 bf16
    __hip_bfloat16* concat = (__hip_bfloat16*)((char*)d_ws + 5234688);  // 1310720 bf16
    __hip_bfloat16* WoutT  = (__hip_bfloat16*)((char*)d_ws + 7856128);  // 491520 bf16
    float* part = (float*)((char*)d_ws + 8847360);                      // 4096*1280 fp32
    __hip_bfloat16* v_sT = (__hip_bfloat16*)((char*)d_ws + 29818880);   // 131072 bf16
    __hip_bfloat16* v_pT = (__hip_bfloat16*)((char*)d_ws + 30081024);   // 98304 bf16
    float* out = (float*)d_out;

    hipLaunchKernelGGL(k_pack, dim3(2544), dim3(256), 0, stream,
                       x, Wq_s, Wk_s, Wv_s, Wq_p, Wk_p, Wv_p, xb, WallT);
    hipLaunchKernelGGL(k_prep, dim3(20, 6), dim3(256), 0, stream, Wout, WoutT);
    hipLaunchKernelGGL(k_projm, dim3(16, 14), dim3(256), 0, stream,
                       xb, WallT, q_s, k_s, v_s, praw, v_sT);
    hipLaunchKernelGGL(k_euclid, dim3(1152), dim3(256), 0, stream,
                       praw, r, t, q_p, k_p, v_p, v_pT);
    hipLaunchKernelGGL(k_attn, dim3(4096), dim3(256), 0, stream,
                       e, Wpb, gamma, q_s, k_s, q_p, k_p, v_sT, v_pT, part);
    hipLaunchKernelGGL(k_comb, dim3(1024), dim3(256), 0, stream,
                       part, r, t, concat);
    hipLaunchKernelGGL(k_out, dim3(16, 6), dim3(256), 0, stream, concat, WoutT, bout, out);
}